// Round 5
// baseline (78.936 us; speedup 1.0000x reference)
//
#include <hip/hip_runtime.h>
#include <hip/hip_bf16.h>
#include <math.h>

#define BDIM 4096
#define DDIM 256
#define N2   8192
#define NSLAB 32             // row slabs of 256
#define NCH 64               // col chunks of 128
#define BN 32                // col tile (16 KB LDS per buffer)
#define NT 4                 // tiles per block (128 cols)
#define TILEB (BN * DDIM * 2)  // 16384 B
#define NBLK 1056            // sum_{I=0}^{31} (64 - 2I)

typedef __bf16 bf16x8 __attribute__((ext_vector_type(8)));
typedef __bf16 bf16x4 __attribute__((ext_vector_type(4)));
typedef float  f32x4  __attribute__((ext_vector_type(4)));

#define WAITVM(N) asm volatile("s_waitcnt vmcnt(" #N ")" ::: "memory")

__device__ __forceinline__ void gload_lds16(const __bf16* g, void* lds) {
    __builtin_amdgcn_global_load_lds(
        (const __attribute__((address_space(1))) unsigned int*)g,
        (__attribute__((address_space(3))) unsigned int*)lds, 16, 0, 0);
}

// ---------------- Kernel 1: L2-normalize rows, emit bf16 reps + fp32 positive dots ----------------
__global__ __launch_bounds__(256) void norm_kernel(const float* __restrict__ z1,
                                                   const float* __restrict__ z2,
                                                   __bf16* __restrict__ reps,
                                                   float* __restrict__ pos) {
    int gwave = (blockIdx.x * 256 + threadIdx.x) >> 6;
    int lane  = threadIdx.x & 63;
    if (gwave >= BDIM) return;

    const float4 a = *(const float4*)&z1[(size_t)gwave * DDIM + lane * 4];
    const float4 b = *(const float4*)&z2[(size_t)gwave * DDIM + lane * 4];

    float s1 = a.x*a.x + a.y*a.y + a.z*a.z + a.w*a.w;
    float s2 = b.x*b.x + b.y*b.y + b.z*b.z + b.w*b.w;
    float d  = a.x*b.x + a.y*b.y + a.z*b.z + a.w*b.w;
    #pragma unroll
    for (int off = 32; off; off >>= 1) {
        s1 += __shfl_xor(s1, off);
        s2 += __shfl_xor(s2, off);
        d  += __shfl_xor(d,  off);
    }
    float r1 = 1.0f / fmaxf(sqrtf(s1), 1e-12f);
    float r2 = 1.0f / fmaxf(sqrtf(s2), 1e-12f);

    bf16x4 w1, w2;
    w1[0] = (__bf16)(a.x * r1); w1[1] = (__bf16)(a.y * r1);
    w1[2] = (__bf16)(a.z * r1); w1[3] = (__bf16)(a.w * r1);
    w2[0] = (__bf16)(b.x * r2); w2[1] = (__bf16)(b.y * r2);
    w2[2] = (__bf16)(b.z * r2); w2[3] = (__bf16)(b.w * r2);
    *(bf16x4*)&reps[(size_t)gwave * DDIM + lane * 4]          = w1;
    *(bf16x4*)&reps[(size_t)(gwave + BDIM) * DDIM + lane * 4] = w2;

    if (lane == 0) pos[gwave] = d * r1 * r2;
}

// ---------------- Kernel 2: symmetric (triangular) GEMM + exp row/col sums ----------------
// Block (I,c), c >= 2I: rows = slab I (256, 4 waves x 64 in regs), cols = chunk c
// (128). exp(2*sim-2) accumulated into rowsums (slab I) and, for off-slab
// chunks, colsums (chunk-c rows) -- exploiting sim symmetry to halve all work.
// B: 4 x 16KB LDS quad-buffer via global_load_lds(16B), XOR-swizzled source,
// counted vmcnt, raw barriers (fully peeled, no buffer reuse).
__global__ __launch_bounds__(256, 2) void lse6_kernel(const __bf16* __restrict__ reps,
                                                      float* __restrict__ partial) {
    __shared__ __attribute__((aligned(16))) __bf16 Bt[NT][BN * DDIM];  // 64 KB
    __shared__ float colacc[4][128];                                   // 2 KB

    const int tid  = threadIdx.x;
    const int wave = tid >> 6;
    const int lane = tid & 63;
    const int l15  = lane & 15;
    const int lq   = lane >> 4;

    // decode triangular (I, c): I = row slab, c = col chunk, c >= 2I
    int b = blockIdx.x, I = 0;
    while (b >= NCH - 2 * I) { b -= NCH - 2 * I; ++I; }
    const int c = 2 * I + b;
    const bool diag = ((c >> 1) == I);   // chunk inside own slab: rowsum only
    const int r0 = I * 256;
    const int col0 = c * 128;

    // hoist A fragments: 4 groups of 16 rows, full K=256
    bf16x8 afr[4][8];
    #pragma unroll
    for (int g = 0; g < 4; ++g) {
        const __bf16* ap = reps + (size_t)(r0 + wave * 64 + g * 16 + l15) * DDIM + lq * 8;
        #pragma unroll
        for (int ks = 0; ks < 8; ++ks)
            afr[g][ks] = *(const bf16x8*)(ap + ks * 32);
    }

    // precomputed per-lane ds-read byte offsets within one buffer (cx = l15&7
    // since (fg*16)&7 == 0)
    int pre[2][8];
    #pragma unroll
    for (int fg = 0; fg < 2; ++fg)
        #pragma unroll
        for (int ks = 0; ks < 8; ++ks)
            pre[fg][ks] = (fg * 16 + l15) * 512 + (((ks * 4 + lq) ^ (l15 & 7)) << 4);

    // stage pointers (advance by one tile = 32 rows x 256 elems per stage)
    const __bf16* sp[4];
    #pragma unroll
    for (int i = 0; i < 4; ++i) {
        int L  = wave * 4096 + i * 1024 + lane * 16;
        int cc = L >> 9;
        int ch = (L >> 4) & 31;
        sp[i] = reps + (size_t)(col0 + cc) * DDIM + ((ch ^ (cc & 7)) << 3);
    }

    f32x4 S[4];
    #pragma unroll
    for (int g = 0; g < 4; ++g)
        #pragma unroll
        for (int r = 0; r < 4; ++r) S[g][r] = 0.f;

    auto stage = [&](int buf) {
        #pragma unroll
        for (int i = 0; i < 4; ++i) {
            gload_lds16(sp[i], (char*)&Bt[0][0] + buf * TILEB + wave * 4096 + i * 1024);
            sp[i] += BN * DDIM;
        }
    };

    auto compute = [&](int buf, int t) {
        const char* bb = (const char*)&Bt[0][0] + buf * TILEB;
        float cp0 = 0.f, cp1 = 0.f;
        #pragma unroll
        for (int fg = 0; fg < 2; ++fg) {
            bf16x8 bf[8];
            #pragma unroll
            for (int ks = 0; ks < 8; ++ks)
                bf[ks] = *(const bf16x8*)(bb + pre[fg][ks]);

            f32x4 acc[4] = {{0.f,0.f,0.f,0.f},{0.f,0.f,0.f,0.f},
                            {0.f,0.f,0.f,0.f},{0.f,0.f,0.f,0.f}};
            __builtin_amdgcn_s_setprio(1);
            #pragma unroll
            for (int ks = 0; ks < 8; ++ks)
                #pragma unroll
                for (int g = 0; g < 4; ++g)
                    acc[g] = __builtin_amdgcn_mfma_f32_16x16x32_bf16(afr[g][ks], bf[ks], acc[g], 0, 0, 0);
            __builtin_amdgcn_s_setprio(0);

            float cp = 0.f;
            #pragma unroll
            for (int g = 0; g < 4; ++g)
                #pragma unroll
                for (int r = 0; r < 4; ++r) {
                    float e = exp2f(fmaf(acc[g][r], 2.8853900817779268f, -2.8853900817779268f));
                    S[g][r] += e;
                    cp += e;
                }
            if (fg == 0) cp0 = cp; else cp1 = cp;
        }
        if (!diag) {
            // column partials: sum the 4 lq groups (rows), store per column
            cp0 += __shfl_xor(cp0, 16); cp0 += __shfl_xor(cp0, 32);
            cp1 += __shfl_xor(cp1, 16); cp1 += __shfl_xor(cp1, 32);
            if (lq == 0) {
                colacc[wave][t * 32 + l15]      = cp0;
                colacc[wave][t * 32 + 16 + l15] = cp1;
            }
        }
    };

    // fully peeled quad-buffer pipeline (counted vmcnt, no drain until tail)
    stage(0); stage(1);
    stage(2); WAITVM(8); __builtin_amdgcn_s_barrier(); compute(0, 0);
    stage(3); WAITVM(8); __builtin_amdgcn_s_barrier(); compute(1, 1);
    WAITVM(4); __builtin_amdgcn_s_barrier(); compute(2, 2);
    WAITVM(0); __builtin_amdgcn_s_barrier(); compute(3, 3);

    // rowsums: reduce across the 16 column-lanes, write slot = chunk id c
    #pragma unroll
    for (int off = 1; off < 16; off <<= 1)
        #pragma unroll
        for (int g = 0; g < 4; ++g)
            #pragma unroll
            for (int r = 0; r < 4; ++r) S[g][r] += __shfl_xor(S[g][r], off);

    if (l15 == 0) {
        #pragma unroll
        for (int g = 0; g < 4; ++g)
            #pragma unroll
            for (int r = 0; r < 4; ++r)
                partial[(size_t)c * N2 + r0 + wave * 64 + g * 16 + lq * 4 + r] = S[g][r];
    }

    // colsums: combine 4 waves, write slot = 64 + I, rows = chunk-c cols
    if (!diag) {
        __syncthreads();
        if (tid < 128) {
            float s = colacc[0][tid] + colacc[1][tid] + colacc[2][tid] + colacc[3][tid];
            partial[(size_t)(NCH + I) * N2 + col0 + tid] = s;
        }
    }
}

// ---------------- Kernel 3a: per-row sum of written slots, log, per-block sums ----------------
__global__ __launch_bounds__(256) void finish1_kernel(const float* __restrict__ partial,
                                                      float* __restrict__ blocksum) {
    int row = blockIdx.x * 256 + threadIdx.x;
    int T = row >> 8;                    // uniform within the block
    float s = -1.0f;                     // remove diagonal self-term exp(0)=1
    for (int cc = 2 * T; cc < NCH; ++cc) s += partial[(size_t)cc * N2 + row];
    for (int i = 0; i < T; ++i)          s += partial[(size_t)(NCH + i) * N2 + row];
    float v = logf(s);
    #pragma unroll
    for (int off = 32; off; off >>= 1) v += __shfl_xor(v, off);
    __shared__ float ws4[4];
    if ((threadIdx.x & 63) == 0) ws4[threadIdx.x >> 6] = v;
    __syncthreads();
    if (threadIdx.x == 0) blocksum[blockIdx.x] = ws4[0] + ws4[1] + ws4[2] + ws4[3];
}

// ---------------- Kernel 3b: final scalar ----------------
__global__ __launch_bounds__(256) void finish2_kernel(const float* __restrict__ blocksum,
                                                      const float* __restrict__ pos,
                                                      float* __restrict__ out) {
    float v = (threadIdx.x < 32) ? blocksum[threadIdx.x] : 0.f;
    float p = 0.f;
    for (int i = threadIdx.x; i < BDIM; i += 256) p += pos[i];
    float t = v - 4.0f * p;
    #pragma unroll
    for (int off = 32; off; off >>= 1) t += __shfl_xor(t, off);
    __shared__ float ws4[4];
    if ((threadIdx.x & 63) == 0) ws4[threadIdx.x >> 6] = t;
    __syncthreads();
    if (threadIdx.x == 0)
        out[0] = 2.0f + (ws4[0] + ws4[1] + ws4[2] + ws4[3]) / (float)N2;
}

extern "C" void kernel_launch(void* const* d_in, const int* in_sizes, int n_in,
                              void* d_out, int out_size, void* d_ws, size_t ws_size,
                              hipStream_t stream) {
    const float* z1 = (const float*)d_in[0];
    const float* z2 = (const float*)d_in[1];
    float* out = (float*)d_out;

    __bf16* reps     = (__bf16*)d_ws;                                  // 4 MB
    float*  partial  = (float*)((char*)d_ws + (size_t)N2 * DDIM * 2);  // 96*8192*4 = 3 MB
    float*  pos      = partial + (size_t)96 * N2;                      // 16 KB
    float*  blocksum = pos + BDIM;                                     // 128 B

    norm_kernel<<<BDIM / 4, 256, 0, stream>>>(z1, z2, reps, pos);
    lse6_kernel<<<NBLK, 256, 0, stream>>>(reps, partial);
    finish1_kernel<<<N2 / 256, 256, 0, stream>>>(partial, blocksum);
    finish2_kernel<<<1, 256, 0, stream>>>(blocksum, pos, out);
}

// Round 6
// 60.741 us; speedup vs baseline: 1.2996x; 1.2996x over previous
//
#include <hip/hip_runtime.h>
#include <hip/hip_bf16.h>
#include <math.h>

#define BDIM 4096
#define DDIM 256
#define N2   8192
#define CSPLIT 32            // 32 col slices of 256
#define BROWS 256            // rows per block (4 waves x 64 rows)
#define BN 32                // col tile
#define NT 8                 // tiles per block (256 cols)
#define TILEB (BN * DDIM)    // 8192 bytes per fp8 tile
#define RING 4

typedef float f32x4 __attribute__((ext_vector_type(4)));
typedef long  i64x2 __attribute__((ext_vector_type(2)));

#define WAITVM(N) asm volatile("s_waitcnt vmcnt(" #N ")" ::: "memory")

__device__ __forceinline__ void gload_lds16(const void* g, void* lds) {
    __builtin_amdgcn_global_load_lds(
        (const __attribute__((address_space(1))) unsigned int*)g,
        (__attribute__((address_space(3))) unsigned int*)lds, 16, 0, 0);
}

// K-byte permutation within a 256-byte row: k -> (k>>6)*64 + ((k>>3)&3)*16
// + ((k>>5)&1)*8 + (k&7). A b128 read at p*64+lq*16 then yields the two 8B
// fragments for MFMA k-slices 2p and 2p+1 at quarter-wave lq.

// ---------------- Kernel 1: L2-normalize rows, emit permuted fp8 reps + fp32 pos ----------------
__global__ __launch_bounds__(256) void norm_kernel(const float* __restrict__ z1,
                                                   const float* __restrict__ z2,
                                                   unsigned char* __restrict__ reps,
                                                   float* __restrict__ pos) {
    int gwave = (blockIdx.x * 256 + threadIdx.x) >> 6;
    int lane  = threadIdx.x & 63;
    if (gwave >= BDIM) return;

    const float4 a = *(const float4*)&z1[(size_t)gwave * DDIM + lane * 4];
    const float4 b = *(const float4*)&z2[(size_t)gwave * DDIM + lane * 4];

    float s1 = a.x*a.x + a.y*a.y + a.z*a.z + a.w*a.w;
    float s2 = b.x*b.x + b.y*b.y + b.z*b.z + b.w*b.w;
    float d  = a.x*b.x + a.y*b.y + a.z*b.z + a.w*b.w;
    #pragma unroll
    for (int off = 32; off; off >>= 1) {
        s1 += __shfl_xor(s1, off);
        s2 += __shfl_xor(s2, off);
        d  += __shfl_xor(d,  off);
    }
    float r1 = 1.0f / fmaxf(sqrtf(s1), 1e-12f);
    float r2 = 1.0f / fmaxf(sqrtf(s2), 1e-12f);

    // permuted byte position of k = lane*4
    int p   = lane >> 4;
    int odd = (lane >> 3) & 1;
    int lqp = (lane >> 1) & 3;
    int w   = (lane & 1) * 4;
    int posb = p * 64 + lqp * 16 + odd * 8 + w;

    int pk1 = __builtin_amdgcn_cvt_pk_fp8_f32(a.x * r1, a.y * r1, 0, false);
    pk1     = __builtin_amdgcn_cvt_pk_fp8_f32(a.z * r1, a.w * r1, pk1, true);
    int pk2 = __builtin_amdgcn_cvt_pk_fp8_f32(b.x * r2, b.y * r2, 0, false);
    pk2     = __builtin_amdgcn_cvt_pk_fp8_f32(b.z * r2, b.w * r2, pk2, true);

    *(int*)(reps + (size_t)gwave * DDIM + posb)          = pk1;
    *(int*)(reps + (size_t)(gwave + BDIM) * DDIM + posb) = pk2;

    if (lane == 0) pos[gwave] = d * r1 * r2;
}

// ---------------- Kernel 2: fp8 GEMM (reps @ reps^T) + exp row sums ----------------
// 1024 blocks (32 rowgroups x 32 colslices) = exactly 4/CU. 4 waves x 64 rows.
// A: 64 rows x K=256 fp8 in 64 VGPRs. B: 8 KB tiles through a 4-buffer LDS ring
// (32 KB) via global_load_lds(16B), XOR-swizzled source, counted vmcnt.
__global__ __launch_bounds__(256, 4) void lse8_kernel(const unsigned char* __restrict__ reps,
                                                      float* __restrict__ partial) {
    __shared__ __attribute__((aligned(16))) unsigned char Bt[RING * TILEB];  // 32 KB

    const int tid  = threadIdx.x;
    const int wave = tid >> 6;
    const int lane = tid & 63;
    const int l15  = lane & 15;
    const int lq   = lane >> 4;
    const int rg   = blockIdx.x >> 5;
    const int cs   = blockIdx.x & 31;
    const int r0   = rg * BROWS;
    const int col0 = cs * 256;

    // hoist A fragments: 4 groups of 16 rows, K=256 (8 slices as i64 each)
    long afr[4][8];
    #pragma unroll
    for (int g = 0; g < 4; ++g) {
        const unsigned char* ap = reps + (size_t)(r0 + wave * 64 + g * 16 + l15) * DDIM + lq * 16;
        #pragma unroll
        for (int p = 0; p < 4; ++p) {
            i64x2 t = *(const i64x2*)(ap + p * 64);
            afr[g][2 * p]     = t[0];
            afr[g][2 * p + 1] = t[1];
        }
    }

    // per-lane B ds_read byte offsets within a column (XOR bank swizzle)
    int qoff[4];
    #pragma unroll
    for (int p = 0; p < 4; ++p)
        qoff[p] = (((p * 4 + lq) ^ l15) << 4);

    // stage source pointers: dest D = wave*2048 + i*1024 + lane*16 (linear),
    // source granule = destgranule ^ (tilecol & 15)  [m173 pre-swizzle]
    const unsigned char* sp[2];
    #pragma unroll
    for (int i = 0; i < 2; ++i) {
        int D  = wave * 2048 + i * 1024 + lane * 16;
        int tc = D >> 8;
        int gq = ((D >> 4) & 15) ^ (tc & 15);
        sp[i] = reps + (size_t)(col0 + tc) * DDIM + (gq << 4);
    }

    f32x4 S[4];
    #pragma unroll
    for (int g = 0; g < 4; ++g)
        #pragma unroll
        for (int r = 0; r < 4; ++r) S[g][r] = 0.f;

    auto stage = [&](int buf) {
        #pragma unroll
        for (int i = 0; i < 2; ++i) {
            gload_lds16(sp[i], &Bt[buf * TILEB + wave * 2048 + i * 1024]);
            sp[i] += BN * DDIM;   // next tile (+8192 B)
        }
    };

    auto compute = [&](int buf) {
        const unsigned char* bb = &Bt[buf * TILEB];
        #pragma unroll
        for (int fg = 0; fg < 2; ++fg) {
            const unsigned char* colp = bb + (fg * 16 + l15) * 256;
            f32x4 acc[4] = {{0.f,0.f,0.f,0.f},{0.f,0.f,0.f,0.f},
                            {0.f,0.f,0.f,0.f},{0.f,0.f,0.f,0.f}};
            __builtin_amdgcn_s_setprio(1);
            #pragma unroll
            for (int p = 0; p < 4; ++p) {
                i64x2 bv = *(const i64x2*)(colp + qoff[p]);
                #pragma unroll
                for (int g = 0; g < 4; ++g)
                    acc[g] = __builtin_amdgcn_mfma_f32_16x16x32_fp8_fp8(afr[g][2*p],   bv[0], acc[g], 0, 0, 0);
                #pragma unroll
                for (int g = 0; g < 4; ++g)
                    acc[g] = __builtin_amdgcn_mfma_f32_16x16x32_fp8_fp8(afr[g][2*p+1], bv[1], acc[g], 0, 0, 0);
            }
            __builtin_amdgcn_s_setprio(0);
            #pragma unroll
            for (int g = 0; g < 4; ++g)
                #pragma unroll
                for (int r = 0; r < 4; ++r)
                    S[g][r] += exp2f(fmaf(acc[g][r], 2.8853900817779268f, -2.8853900817779268f));
        }
    };

    // counted-vmcnt pipeline: RING=4, PD=2, 8 tiles
    stage(0); stage(1);
    #pragma unroll 1
    for (int t = 0; t < NT - 2; ++t) {
        stage((t + 2) & 3);
        WAITVM(4);                      // tile-t loads retired; 4 newer in flight
        __builtin_amdgcn_s_barrier();
        compute(t & 3);
    }
    WAITVM(2); __builtin_amdgcn_s_barrier(); compute((NT - 2) & 3);
    WAITVM(0); __builtin_amdgcn_s_barrier(); compute((NT - 1) & 3);

    // reduce across the 16 column-lanes
    #pragma unroll
    for (int off = 1; off < 16; off <<= 1)
        #pragma unroll
        for (int g = 0; g < 4; ++g)
            #pragma unroll
            for (int r = 0; r < 4; ++r) S[g][r] += __shfl_xor(S[g][r], off);

    if (l15 == 0) {
        #pragma unroll
        for (int g = 0; g < 4; ++g)
            #pragma unroll
            for (int r = 0; r < 4; ++r)
                partial[(size_t)cs * N2 + r0 + wave * 64 + g * 16 + lq * 4 + r] = S[g][r];
    }
}

// ---------------- Kernel 3a: per-row sum of 32 partials, log, per-block sums ----------------
__global__ __launch_bounds__(256) void finish1_kernel(const float* __restrict__ partial,
                                                      float* __restrict__ blocksum) {
    int row = blockIdx.x * 256 + threadIdx.x;
    float s = -1.0f;                     // remove diagonal self-term exp(0)=1
    #pragma unroll
    for (int cc = 0; cc < CSPLIT; ++cc) s += partial[(size_t)cc * N2 + row];
    float v = logf(s);
    #pragma unroll
    for (int off = 32; off; off >>= 1) v += __shfl_xor(v, off);
    __shared__ float ws4[4];
    if ((threadIdx.x & 63) == 0) ws4[threadIdx.x >> 6] = v;
    __syncthreads();
    if (threadIdx.x == 0) blocksum[blockIdx.x] = ws4[0] + ws4[1] + ws4[2] + ws4[3];
}

// ---------------- Kernel 3b: final scalar ----------------
__global__ __launch_bounds__(256) void finish2_kernel(const float* __restrict__ blocksum,
                                                      const float* __restrict__ pos,
                                                      float* __restrict__ out) {
    float v = (threadIdx.x < 32) ? blocksum[threadIdx.x] : 0.f;
    float p = 0.f;
    for (int i = threadIdx.x; i < BDIM; i += 256) p += pos[i];
    float t = v - 4.0f * p;
    #pragma unroll
    for (int off = 32; off; off >>= 1) t += __shfl_xor(t, off);
    __shared__ float ws4[4];
    if ((threadIdx.x & 63) == 0) ws4[threadIdx.x >> 6] = t;
    __syncthreads();
    if (threadIdx.x == 0)
        out[0] = 2.0f + (ws4[0] + ws4[1] + ws4[2] + ws4[3]) / (float)N2;
}

extern "C" void kernel_launch(void* const* d_in, const int* in_sizes, int n_in,
                              void* d_out, int out_size, void* d_ws, size_t ws_size,
                              hipStream_t stream) {
    const float* z1 = (const float*)d_in[0];
    const float* z2 = (const float*)d_in[1];
    float* out = (float*)d_out;

    unsigned char* reps = (unsigned char*)d_ws;                        // 2 MB fp8
    float* partial  = (float*)((char*)d_ws + (size_t)N2 * DDIM);       // 32*8192*4 = 1 MB
    float* pos      = partial + (size_t)CSPLIT * N2;                   // 16 KB
    float* blocksum = pos + BDIM;                                      // 128 B

    norm_kernel<<<BDIM / 4, 256, 0, stream>>>(z1, z2, reps, pos);
    lse8_kernel<<<(N2 / BROWS) * CSPLIT, 256, 0, stream>>>(reps, partial);
    finish1_kernel<<<N2 / 256, 256, 0, stream>>>(partial, blocksum);
    finish2_kernel<<<1, 256, 0, stream>>>(blocksum, pos, out);
}

// Round 7
// 48.467 us; speedup vs baseline: 1.6287x; 1.2532x over previous
//
#include <hip/hip_runtime.h>
#include <hip/hip_bf16.h>
#include <math.h>

#define BDIM 4096
#define DDIM 256
#define N2   8192
#define CSPLIT 32            // 32 col slices of 256
#define BROWS 256            // rows per block (8 waves x 32 rows)
#define BN 32                // col tile
#define NT 8                 // tiles per block (256 cols)
#define TILEB (BN * DDIM)    // 8192 bytes per fp8 tile
#define RING 4

typedef float f32x4 __attribute__((ext_vector_type(4)));
typedef long  i64x2 __attribute__((ext_vector_type(2)));

#define WAITVM(N) asm volatile("s_waitcnt vmcnt(" #N ")" ::: "memory")

__device__ __forceinline__ void gload_lds16(const void* g, void* lds) {
    __builtin_amdgcn_global_load_lds(
        (const __attribute__((address_space(1))) unsigned int*)g,
        (__attribute__((address_space(3))) unsigned int*)lds, 16, 0, 0);
}

// K-byte permutation within a 256-byte row: k -> (k>>6)*64 + ((k>>3)&3)*16
// + ((k>>5)&1)*8 + (k&7). A b128 read at p*64+lq*16 then yields the two 8B
// fragments for MFMA k-slices 2p and 2p+1 at quarter-wave lq.

// ---------------- Kernel 1: L2-normalize rows, emit permuted fp8 reps + fp32 pos ----------------
__global__ __launch_bounds__(256) void norm_kernel(const float* __restrict__ z1,
                                                   const float* __restrict__ z2,
                                                   unsigned char* __restrict__ reps,
                                                   float* __restrict__ pos) {
    int gwave = (blockIdx.x * 256 + threadIdx.x) >> 6;
    int lane  = threadIdx.x & 63;
    if (gwave >= BDIM) return;

    const float4 a = *(const float4*)&z1[(size_t)gwave * DDIM + lane * 4];
    const float4 b = *(const float4*)&z2[(size_t)gwave * DDIM + lane * 4];

    float s1 = a.x*a.x + a.y*a.y + a.z*a.z + a.w*a.w;
    float s2 = b.x*b.x + b.y*b.y + b.z*b.z + b.w*b.w;
    float d  = a.x*b.x + a.y*b.y + a.z*b.z + a.w*b.w;
    #pragma unroll
    for (int off = 32; off; off >>= 1) {
        s1 += __shfl_xor(s1, off);
        s2 += __shfl_xor(s2, off);
        d  += __shfl_xor(d,  off);
    }
    float r1 = 1.0f / fmaxf(sqrtf(s1), 1e-12f);
    float r2 = 1.0f / fmaxf(sqrtf(s2), 1e-12f);

    // permuted byte position of k = lane*4
    int p   = lane >> 4;
    int odd = (lane >> 3) & 1;
    int lqp = (lane >> 1) & 3;
    int w   = (lane & 1) * 4;
    int posb = p * 64 + lqp * 16 + odd * 8 + w;

    int pk1 = __builtin_amdgcn_cvt_pk_fp8_f32(a.x * r1, a.y * r1, 0, false);
    pk1     = __builtin_amdgcn_cvt_pk_fp8_f32(a.z * r1, a.w * r1, pk1, true);
    int pk2 = __builtin_amdgcn_cvt_pk_fp8_f32(b.x * r2, b.y * r2, 0, false);
    pk2     = __builtin_amdgcn_cvt_pk_fp8_f32(b.z * r2, b.w * r2, pk2, true);

    *(int*)(reps + (size_t)gwave * DDIM + posb)          = pk1;
    *(int*)(reps + (size_t)(gwave + BDIM) * DDIM + posb) = pk2;

    if (lane == 0) pos[gwave] = d * r1 * r2;
}

// ---------------- Kernel 2: fp8 GEMM (reps @ reps^T) + exp row sums ----------------
// 1024 blocks (32 rowgroups x 32 colslices), 512 threads = 8 waves x 32 rows.
// A: 32 rows x K=256 fp8 in 32 VGPRs/wave (~72 total -> no spill at the
// 128-reg/wave budget of 2 blocks/CU). B: 8 KB tiles through a 4-buffer LDS
// ring via global_load_lds(16B) (exactly 1 per wave per tile), XOR-swizzled
// source (zero bank conflicts, verified r6), counted vmcnt, raw barriers.
__global__ __launch_bounds__(512, 4) void lse9_kernel(const unsigned char* __restrict__ reps,
                                                      float* __restrict__ partial) {
    __shared__ __attribute__((aligned(16))) unsigned char Bt[RING * TILEB];  // 32 KB

    const int tid  = threadIdx.x;
    const int wave = tid >> 6;
    const int lane = tid & 63;
    const int l15  = lane & 15;
    const int lq   = lane >> 4;
    const int rg   = blockIdx.x >> 5;
    const int cs   = blockIdx.x & 31;
    const int r0   = rg * BROWS;
    const int col0 = cs * 256;

    // hoist A fragments: 2 groups of 16 rows (this wave's 32 rows), K=256
    long afr0[8], afr1[8];
    {
        const unsigned char* a0 = reps + (size_t)(r0 + wave * 32 + l15) * DDIM + lq * 16;
        const unsigned char* a1 = a0 + 16 * DDIM;
        #pragma unroll
        for (int p = 0; p < 4; ++p) {
            i64x2 t0 = *(const i64x2*)(a0 + p * 64);
            i64x2 t1 = *(const i64x2*)(a1 + p * 64);
            afr0[2*p] = t0[0]; afr0[2*p+1] = t0[1];
            afr1[2*p] = t1[0]; afr1[2*p+1] = t1[1];
        }
    }

    // per-lane B ds_read byte offsets within a column (XOR bank swizzle)
    int qoff[4];
    #pragma unroll
    for (int p = 0; p < 4; ++p)
        qoff[p] = (((p * 4 + lq) ^ l15) << 4);

    // stage source pointer: dest D = tid*16 (linear, whole tile in one shot),
    // source granule = destgranule ^ (tilecol & 15)  [m173 pre-swizzle]
    const unsigned char* sp;
    {
        int D  = tid * 16;
        int tc = D >> 8;
        int gq = ((D >> 4) & 15) ^ (tc & 15);
        sp = reps + (size_t)(col0 + tc) * DDIM + (gq << 4);
    }

    f32x4 S0 = {0.f,0.f,0.f,0.f}, S1 = {0.f,0.f,0.f,0.f};

    auto stage = [&](int buf) {
        gload_lds16(sp, &Bt[buf * TILEB + tid * 16]);
        sp += BN * DDIM;   // next tile (+8192 B)
    };

    auto compute = [&](int buf) {
        const unsigned char* bb = &Bt[buf * TILEB];
        #pragma unroll
        for (int fg = 0; fg < 2; ++fg) {
            const unsigned char* colp = bb + (fg * 16 + l15) * 256;
            f32x4 acc0 = {0.f,0.f,0.f,0.f}, acc1 = {0.f,0.f,0.f,0.f};
            __builtin_amdgcn_s_setprio(1);
            #pragma unroll
            for (int p = 0; p < 4; ++p) {
                i64x2 bv = *(const i64x2*)(colp + qoff[p]);
                acc0 = __builtin_amdgcn_mfma_f32_16x16x32_fp8_fp8(afr0[2*p],   bv[0], acc0, 0, 0, 0);
                acc1 = __builtin_amdgcn_mfma_f32_16x16x32_fp8_fp8(afr1[2*p],   bv[0], acc1, 0, 0, 0);
                acc0 = __builtin_amdgcn_mfma_f32_16x16x32_fp8_fp8(afr0[2*p+1], bv[1], acc0, 0, 0, 0);
                acc1 = __builtin_amdgcn_mfma_f32_16x16x32_fp8_fp8(afr1[2*p+1], bv[1], acc1, 0, 0, 0);
            }
            __builtin_amdgcn_s_setprio(0);
            #pragma unroll
            for (int r = 0; r < 4; ++r) {
                S0[r] += exp2f(fmaf(acc0[r], 2.8853900817779268f, -2.8853900817779268f));
                S1[r] += exp2f(fmaf(acc1[r], 2.8853900817779268f, -2.8853900817779268f));
            }
        }
    };

    // counted-vmcnt pipeline: RING=4, PD=2, 8 tiles, 1 load/wave/tile
    stage(0); stage(1);
    #pragma unroll 1
    for (int t = 0; t < NT - 2; ++t) {
        stage((t + 2) & 3);
        WAITVM(2);                      // tile-t load retired; 2 newer in flight
        __builtin_amdgcn_s_barrier();
        compute(t & 3);
    }
    WAITVM(1); __builtin_amdgcn_s_barrier(); compute((NT - 2) & 3);
    WAITVM(0); __builtin_amdgcn_s_barrier(); compute((NT - 1) & 3);

    // reduce across the 16 column-lanes
    #pragma unroll
    for (int off = 1; off < 16; off <<= 1) {
        #pragma unroll
        for (int r = 0; r < 4; ++r) {
            S0[r] += __shfl_xor(S0[r], off);
            S1[r] += __shfl_xor(S1[r], off);
        }
    }

    if (l15 == 0) {
        #pragma unroll
        for (int r = 0; r < 4; ++r) {
            partial[(size_t)cs * N2 + r0 + wave * 32 + lq * 4 + r]      = S0[r];
            partial[(size_t)cs * N2 + r0 + wave * 32 + 16 + lq * 4 + r] = S1[r];
        }
    }
}

// ---------------- Kernel 3a: per-row sum of 32 partials, log, per-block sums ----------------
__global__ __launch_bounds__(256) void finish1_kernel(const float* __restrict__ partial,
                                                      float* __restrict__ blocksum) {
    int row = blockIdx.x * 256 + threadIdx.x;
    float s = -1.0f;                     // remove diagonal self-term exp(0)=1
    #pragma unroll
    for (int cc = 0; cc < CSPLIT; ++cc) s += partial[(size_t)cc * N2 + row];
    float v = logf(s);
    #pragma unroll
    for (int off = 32; off; off >>= 1) v += __shfl_xor(v, off);
    __shared__ float ws4[4];
    if ((threadIdx.x & 63) == 0) ws4[threadIdx.x >> 6] = v;
    __syncthreads();
    if (threadIdx.x == 0) blocksum[blockIdx.x] = ws4[0] + ws4[1] + ws4[2] + ws4[3];
}

// ---------------- Kernel 3b: final scalar ----------------
__global__ __launch_bounds__(256) void finish2_kernel(const float* __restrict__ blocksum,
                                                      const float* __restrict__ pos,
                                                      float* __restrict__ out) {
    float v = (threadIdx.x < 32) ? blocksum[threadIdx.x] : 0.f;
    float p = 0.f;
    for (int i = threadIdx.x; i < BDIM; i += 256) p += pos[i];
    float t = v - 4.0f * p;
    #pragma unroll
    for (int off = 32; off; off >>= 1) t += __shfl_xor(t, off);
    __shared__ float ws4[4];
    if ((threadIdx.x & 63) == 0) ws4[threadIdx.x >> 6] = t;
    __syncthreads();
    if (threadIdx.x == 0)
        out[0] = 2.0f + (ws4[0] + ws4[1] + ws4[2] + ws4[3]) / (float)N2;
}

extern "C" void kernel_launch(void* const* d_in, const int* in_sizes, int n_in,
                              void* d_out, int out_size, void* d_ws, size_t ws_size,
                              hipStream_t stream) {
    const float* z1 = (const float*)d_in[0];
    const float* z2 = (const float*)d_in[1];
    float* out = (float*)d_out;

    unsigned char* reps = (unsigned char*)d_ws;                        // 2 MB fp8
    float* partial  = (float*)((char*)d_ws + (size_t)N2 * DDIM);       // 32*8192*4 = 1 MB
    float* pos      = partial + (size_t)CSPLIT * N2;                   // 16 KB
    float* blocksum = pos + BDIM;                                      // 128 B

    norm_kernel<<<BDIM / 4, 256, 0, stream>>>(z1, z2, reps, pos);
    lse9_kernel<<<(N2 / BROWS) * CSPLIT, 512, 0, stream>>>(reps, partial);
    finish1_kernel<<<N2 / 256, 256, 0, stream>>>(partial, blocksum);
    finish2_kernel<<<1, 256, 0, stream>>>(blocksum, pos, out);
}

// Round 8
// 42.338 us; speedup vs baseline: 1.8644x; 1.1448x over previous
//
#include <hip/hip_runtime.h>
#include <hip/hip_bf16.h>
#include <math.h>

#define BDIM 4096
#define DDIM 256
#define N2   8192
#define CSPLIT 16            // 16 col slices of 512
#define BROWS 256            // rows per block (8 waves x 32 rows)
#define BN 32                // col tile
#define NT 16                // tiles per block (512 cols)
#define TILEB (BN * DDIM)    // 8192 bytes per fp8 tile
#define RING 4
#define SCALE1 0x7F7F7F7F    // E8M0 127 = 2^0 in every byte

typedef float f32x4 __attribute__((ext_vector_type(4)));
typedef int   i32x4 __attribute__((ext_vector_type(4)));
typedef int   i32x8 __attribute__((ext_vector_type(8)));

#define WAITVM(N) asm volatile("s_waitcnt vmcnt(" #N ")" ::: "memory")

__device__ __forceinline__ void gload_lds16(const void* g, void* lds) {
    __builtin_amdgcn_global_load_lds(
        (const __attribute__((address_space(1))) unsigned int*)g,
        (__attribute__((address_space(3))) unsigned int*)lds, 16, 0, 0);
}

// ---------------- Kernel 1: L2-normalize rows, emit fp8 reps (natural k-order) + fp32 pos ----------------
__global__ __launch_bounds__(256) void norm_kernel(const float* __restrict__ z1,
                                                   const float* __restrict__ z2,
                                                   unsigned char* __restrict__ reps,
                                                   float* __restrict__ pos) {
    int gwave = (blockIdx.x * 256 + threadIdx.x) >> 6;
    int lane  = threadIdx.x & 63;
    if (gwave >= BDIM) return;

    const float4 a = *(const float4*)&z1[(size_t)gwave * DDIM + lane * 4];
    const float4 b = *(const float4*)&z2[(size_t)gwave * DDIM + lane * 4];

    float s1 = a.x*a.x + a.y*a.y + a.z*a.z + a.w*a.w;
    float s2 = b.x*b.x + b.y*b.y + b.z*b.z + b.w*b.w;
    float d  = a.x*b.x + a.y*b.y + a.z*b.z + a.w*b.w;
    #pragma unroll
    for (int off = 32; off; off >>= 1) {
        s1 += __shfl_xor(s1, off);
        s2 += __shfl_xor(s2, off);
        d  += __shfl_xor(d,  off);
    }
    float r1 = 1.0f / fmaxf(sqrtf(s1), 1e-12f);
    float r2 = 1.0f / fmaxf(sqrtf(s2), 1e-12f);

    int pk1 = __builtin_amdgcn_cvt_pk_fp8_f32(a.x * r1, a.y * r1, 0, false);
    pk1     = __builtin_amdgcn_cvt_pk_fp8_f32(a.z * r1, a.w * r1, pk1, true);
    int pk2 = __builtin_amdgcn_cvt_pk_fp8_f32(b.x * r2, b.y * r2, 0, false);
    pk2     = __builtin_amdgcn_cvt_pk_fp8_f32(b.z * r2, b.w * r2, pk2, true);

    *(int*)(reps + (size_t)gwave * DDIM + lane * 4)          = pk1;
    *(int*)(reps + (size_t)(gwave + BDIM) * DDIM + lane * 4) = pk2;

    if (lane == 0) pos[gwave] = d * r1 * r2;
}

// ---------------- Kernel 2: MX-fp8 GEMM (reps @ reps^T, K=128 scaled MFMA) + exp row sums ----------------
// 512 blocks (32 rowgroups x 16 colslices) = exactly 2/CU. 8 waves x 32 rows.
// A: 32 rows x K=256 fp8 in 32 VGPRs/wave (2 rowgroups x 2 K-halves as i32x8).
// B: 8 KB tiles through a 4-buffer LDS ring via global_load_lds(16B), XOR-
// granule-swizzled source (conflict-free b128 reads), counted vmcnt, raw
// barriers. MFMA: mfma_scale_f32_16x16x128_f8f6f4 with unit scales (2x rate
// of non-scaled fp8). Lane layout: A row=l&15 k-chunk=(l>>4)*32; B col=l&15.
__global__ __launch_bounds__(512, 4) void lse10_kernel(const unsigned char* __restrict__ reps,
                                                       float* __restrict__ partial) {
    __shared__ __attribute__((aligned(16))) unsigned char Bt[RING * TILEB];  // 32 KB

    const int tid  = threadIdx.x;
    const int wave = tid >> 6;
    const int lane = tid & 63;
    const int l15  = lane & 15;
    const int lq   = lane >> 4;
    const int rg   = blockIdx.x >> 4;
    const int cs   = blockIdx.x & 15;
    const int r0   = rg * BROWS;
    const int col0 = cs * (BN * NT);

    // hoist A fragments: 2 rowgroups x 2 K-halves, 32B/lane each (natural order)
    i32x8 afr0[2], afr1[2];
    {
        const unsigned char* a0 = reps + (size_t)(r0 + wave * 32 + l15) * DDIM + lq * 32;
        const unsigned char* a1 = a0 + 16 * DDIM;
        #pragma unroll
        for (int m = 0; m < 2; ++m) {
            i32x4 lo0 = *(const i32x4*)(a0 + m * 128);
            i32x4 hi0 = *(const i32x4*)(a0 + m * 128 + 16);
            i32x4 lo1 = *(const i32x4*)(a1 + m * 128);
            i32x4 hi1 = *(const i32x4*)(a1 + m * 128 + 16);
            afr0[m] = __builtin_shufflevector(lo0, hi0, 0, 1, 2, 3, 4, 5, 6, 7);
            afr1[m] = __builtin_shufflevector(lo1, hi1, 0, 1, 2, 3, 4, 5, 6, 7);
        }
    }

    // per-lane B ds_read byte offsets: logical granule q = m*8+lq*2+h of col
    // l15 sits at physical granule q^l15 (involutive XOR swizzle)
    int qo[2][2];
    #pragma unroll
    for (int m = 0; m < 2; ++m)
        #pragma unroll
        for (int h = 0; h < 2; ++h)
            qo[m][h] = (((m * 8 + lq * 2 + h) ^ l15) << 4);

    // stage source pointer: dest D = tid*16 (linear), source granule = destG ^ (col&15)
    const unsigned char* sp;
    {
        int D  = tid * 16;
        int tc = D >> 8;
        int gq = ((D >> 4) & 15) ^ (tc & 15);
        sp = reps + (size_t)(col0 + tc) * DDIM + (gq << 4);
    }

    f32x4 S0 = {0.f,0.f,0.f,0.f}, S1 = {0.f,0.f,0.f,0.f};

    auto stage = [&](int buf) {
        gload_lds16(sp, &Bt[buf * TILEB + tid * 16]);
        sp += BN * DDIM;   // next tile (+8192 B)
    };

    auto compute = [&](int buf) {
        const unsigned char* bb = &Bt[buf * TILEB];
        #pragma unroll
        for (int fg = 0; fg < 2; ++fg) {
            const unsigned char* colp = bb + (fg * 16 + l15) * 256;
            f32x4 acc0 = {0.f,0.f,0.f,0.f}, acc1 = {0.f,0.f,0.f,0.f};
            __builtin_amdgcn_s_setprio(1);
            #pragma unroll
            for (int m = 0; m < 2; ++m) {
                i32x4 lo = *(const i32x4*)(colp + qo[m][0]);
                i32x4 hi = *(const i32x4*)(colp + qo[m][1]);
                i32x8 bv = __builtin_shufflevector(lo, hi, 0, 1, 2, 3, 4, 5, 6, 7);
                acc0 = __builtin_amdgcn_mfma_scale_f32_16x16x128_f8f6f4(
                           afr0[m], bv, acc0, 0, 0, 0, SCALE1, 0, SCALE1);
                acc1 = __builtin_amdgcn_mfma_scale_f32_16x16x128_f8f6f4(
                           afr1[m], bv, acc1, 0, 0, 0, SCALE1, 0, SCALE1);
            }
            __builtin_amdgcn_s_setprio(0);
            #pragma unroll
            for (int r = 0; r < 4; ++r) {
                S0[r] += exp2f(fmaf(acc0[r], 2.8853900817779268f, -2.8853900817779268f));
                S1[r] += exp2f(fmaf(acc1[r], 2.8853900817779268f, -2.8853900817779268f));
            }
        }
    };

    // counted-vmcnt pipeline: RING=4, PD=2, 16 tiles, 1 load/wave/tile
    stage(0); stage(1);
    #pragma unroll 1
    for (int t = 0; t < NT - 2; ++t) {
        stage((t + 2) & 3);
        WAITVM(2);                      // tile-t load retired; 2 newer in flight
        __builtin_amdgcn_s_barrier();
        compute(t & 3);
    }
    WAITVM(1); __builtin_amdgcn_s_barrier(); compute((NT - 2) & 3);
    WAITVM(0); __builtin_amdgcn_s_barrier(); compute((NT - 1) & 3);

    // reduce across the 16 column-lanes
    #pragma unroll
    for (int off = 1; off < 16; off <<= 1) {
        #pragma unroll
        for (int r = 0; r < 4; ++r) {
            S0[r] += __shfl_xor(S0[r], off);
            S1[r] += __shfl_xor(S1[r], off);
        }
    }

    if (l15 == 0) {
        #pragma unroll
        for (int r = 0; r < 4; ++r) {
            partial[(size_t)cs * N2 + r0 + wave * 32 + lq * 4 + r]      = S0[r];
            partial[(size_t)cs * N2 + r0 + wave * 32 + 16 + lq * 4 + r] = S1[r];
        }
    }
}

// ---------------- Kernel 3a: per-row sum of partials, log, per-block sums ----------------
__global__ __launch_bounds__(256) void finish1_kernel(const float* __restrict__ partial,
                                                      float* __restrict__ blocksum) {
    int row = blockIdx.x * 256 + threadIdx.x;
    float s = -1.0f;                     // remove diagonal self-term exp(0)=1
    #pragma unroll
    for (int cc = 0; cc < CSPLIT; ++cc) s += partial[(size_t)cc * N2 + row];
    float v = logf(s);
    #pragma unroll
    for (int off = 32; off; off >>= 1) v += __shfl_xor(v, off);
    __shared__ float ws4[4];
    if ((threadIdx.x & 63) == 0) ws4[threadIdx.x >> 6] = v;
    __syncthreads();
    if (threadIdx.x == 0) blocksum[blockIdx.x] = ws4[0] + ws4[1] + ws4[2] + ws4[3];
}

// ---------------- Kernel 3b: final scalar ----------------
__global__ __launch_bounds__(256) void finish2_kernel(const float* __restrict__ blocksum,
                                                      const float* __restrict__ pos,
                                                      float* __restrict__ out) {
    float v = (threadIdx.x < 32) ? blocksum[threadIdx.x] : 0.f;
    float p = 0.f;
    for (int i = threadIdx.x; i < BDIM; i += 256) p += pos[i];
    float t = v - 4.0f * p;
    #pragma unroll
    for (int off = 32; off; off >>= 1) t += __shfl_xor(t, off);
    __shared__ float ws4[4];
    if ((threadIdx.x & 63) == 0) ws4[threadIdx.x >> 6] = t;
    __syncthreads();
    if (threadIdx.x == 0)
        out[0] = 2.0f + (ws4[0] + ws4[1] + ws4[2] + ws4[3]) / (float)N2;
}

extern "C" void kernel_launch(void* const* d_in, const int* in_sizes, int n_in,
                              void* d_out, int out_size, void* d_ws, size_t ws_size,
                              hipStream_t stream) {
    const float* z1 = (const float*)d_in[0];
    const float* z2 = (const float*)d_in[1];
    float* out = (float*)d_out;

    unsigned char* reps = (unsigned char*)d_ws;                        // 2 MB fp8
    float* partial  = (float*)((char*)d_ws + (size_t)N2 * DDIM);       // 16*8192*4 = 512 KB
    float* pos      = partial + (size_t)CSPLIT * N2;                   // 16 KB
    float* blocksum = pos + BDIM;                                      // 128 B

    norm_kernel<<<BDIM / 4, 256, 0, stream>>>(z1, z2, reps, pos);
    lse10_kernel<<<(N2 / BROWS) * CSPLIT, 512, 0, stream>>>(reps, partial);
    finish1_kernel<<<N2 / 256, 256, 0, stream>>>(partial, blocksum);
    finish2_kernel<<<1, 256, 0, stream>>>(blocksum, pos, out);
}